// Round 7
// baseline (260.320 us; speedup 1.0000x reference)
//
#include <hip/hip_runtime.h>

// BiLSTM: LSTM(B=2048,T=256,F=H=128) + linear head, fused, one block/CU.
// Round 6 (resubmit after infra failure): TWO independent recurrence streams
// per block (batches even/odd, 4 rows each). Each stream: own compact hbuf
// [4][128] (4-way broadcast reads: every lane reads row c16>>2 -> all 16
// A-rows real -> all D-rows redundant -> extract gh[n][0]), own 16-MFMA
// h-chain + ELEM. The two chains are register-independent -> they overlap
// and fill each other's latency (read latency, MFMA chain, trans chain).
// x-matmul shared: A-row = batch*2 + step (16 real rows), 8 x-MFMA/step.

typedef __attribute__((ext_vector_type(8))) short short8;
typedef __attribute__((ext_vector_type(4))) float f32x4;
typedef __attribute__((ext_vector_type(2))) float f32x2;

#define T_STEPS 256
#define L2E 1.4426950408889634f

__device__ __forceinline__ unsigned int cvt_pk_bf16(float lo, float hi) {
    unsigned int r;
    asm volatile("v_cvt_pk_bf16_f32 %0, %1, %2" : "=v"(r) : "v"(lo), "v"(hi));
    return r;
}
__device__ __forceinline__ unsigned short f2bf(float f) {
    unsigned int u = __builtin_bit_cast(unsigned int, f);
    u += 0x7fffu + ((u >> 16) & 1u);   // RNE
    return (unsigned short)(u >> 16);
}
__device__ __forceinline__ float rcp_fast(float x) { return __builtin_amdgcn_rcpf(x); }
__device__ __forceinline__ float exp2f_fast(float x) { return __builtin_amdgcn_exp2f(x); }

__device__ __forceinline__ short8 pack8(const f32x4 a, const f32x4 b) {
    short8 v;
    v[0] = (short)f2bf(a[0]); v[1] = (short)f2bf(a[1]);
    v[2] = (short)f2bf(a[2]); v[3] = (short)f2bf(a[3]);
    v[4] = (short)f2bf(b[0]); v[5] = (short)f2bf(b[1]);
    v[6] = (short)f2bf(b[2]); v[7] = (short)f2bf(b[3]);
    return v;
}

// barrier that drains LDS ops only; VMEM prefetches stay in flight
#define LBAR() asm volatile("s_waitcnt lgkmcnt(0)\n\ts_barrier" ::: "memory")

#define MFMA16(A, B, C) __builtin_amdgcn_mfma_f32_16x16x32_bf16((A), (B), (C), 0, 0, 0)

// one element: gates = gX[n][J] + GH[n][0]; 5 exp + 2 rcp
#define GATE1(J, GH, CS, OH)                                                   \
  { float gi = gX[0][J] + GH[0][0];                                            \
    float gf = gX[1][J] + GH[1][0];                                            \
    float gg = gX[2][J] + GH[2][0];                                            \
    float go = gX[3][J] + GH[3][0];                                            \
    float ef = exp2f_fast(gf * L2E);                                           \
    float ei = exp2f_fast(gi * L2E);                                           \
    float eg = exp2f_fast(gg * (2.f * L2E));                                   \
    float Fq = ef + 1.f, Iq = ei + 1.f, Gq = eg + 1.f;                         \
    float pq = Iq * Gq;                                                        \
    float Rq = rcp_fast(Fq * pq);                                              \
    float cq = __builtin_fmaf(ef * pq, (CS), (ei * Fq) * (eg - 1.f)) * Rq;     \
    (CS) = cq;                                                                 \
    float ccq = fminf(fmaxf(cq, -15.f), 15.f);                                 \
    float eo = exp2f_fast(go * L2E);                                           \
    float ec = exp2f_fast(ccq * (2.f * L2E));                                  \
    (OH) = (eo * (ec - 1.f)) * rcp_fast((eo + 1.f) * (ec + 1.f)); }

// One step. T0 = group start (even), S = step-in-group (0/1 literal),
// GP = xbuf parity of this group. hbuf parity: read [S], write [S^1].
#define STEP(T0, S, GP)                                                        \
  do {                                                                         \
    short8 ah0[4], ah1[4];                                                     \
    _Pragma("unroll")                                                          \
    for (int kt = 0; kt < 4; ++kt) {                                           \
      const int kof = hcp * 128 + ((kt * 32 + kq * 8) ^ (hcp << 4));           \
      ah0[kt] = *reinterpret_cast<const short8*>(&hbuf[0][S][kof]);            \
      ah1[kt] = *reinterpret_cast<const short8*>(&hbuf[1][S][kof]);            \
    }                                                                          \
    f32x4 gh0[4], gh1[4];                                                      \
    _Pragma("unroll")                                                          \
    for (int n = 0; n < 4; ++n) {                                              \
      gh0[n] = (f32x4){0.f, 0.f, 0.f, 0.f};                                    \
      gh1[n] = (f32x4){0.f, 0.f, 0.f, 0.f};                                    \
    }                                                                          \
    _Pragma("unroll")                                                          \
    for (int kt = 0; kt < 4; ++kt) {                                           \
      _Pragma("unroll")                                                        \
      for (int n = 0; n < 4; ++n) {                                            \
        gh0[n] = MFMA16(ah0[kt], bq[kt + 4][n], gh0[n]);                       \
        gh1[n] = MFMA16(ah1[kt], bq[kt + 4][n], gh1[n]);                       \
      }                                                                        \
    }                                                                          \
    if ((S) == 0) { /* x-gates for both steps of the group + prefetch */       \
      short8 afx[4];                                                           \
      _Pragma("unroll")                                                        \
      for (int kt = 0; kt < 4; ++kt) {                                         \
        int idx = (c16 * 128 + kt * 32 + kq * 8) ^ ((c16 & 7) << 3);           \
        afx[kt] = *reinterpret_cast<const short8*>(&xbuf[GP][idx]);            \
      }                                                                        \
      _Pragma("unroll")                                                        \
      for (int n = 0; n < 4; ++n)                                              \
        gX[n] = (f32x4){bias[n], bias[n], bias[n], bias[n]};                   \
      _Pragma("unroll")                                                        \
      for (int kt = 0; kt < 4; ++kt)                                           \
        _Pragma("unroll")                                                      \
        for (int n = 0; n < 4; ++n)                                            \
          gX[n] = MFMA16(afx[kt], bq[kt][n], gX[n]);                           \
      const int tt = ((T0) + 2 < T_STEPS) ? (T0) + 2 : 0;                      \
      nx0 = *reinterpret_cast<const f32x2*>(xrow + (size_t)tt * 128);          \
      nx1 = *reinterpret_cast<const f32x2*>(xrow + (size_t)(tt + 1) * 128);    \
      wlN0 = w_lin[tt * 128 + hid];                                            \
      wlN1 = w_lin[(tt + 1) * 128 + hid];                                      \
    } else { /* stage next group's x from regs prefetched at S=0 */            \
      unsigned int p0 = cvt_pk_bf16(nx0[0], nx0[1]);                           \
      unsigned int p1 = cvt_pk_bf16(nx1[0], nx1[1]);                           \
      *reinterpret_cast<unsigned int*>(&xbuf[(GP) ^ 1][xw0]) = p0;             \
      *reinterpret_cast<unsigned int*>(&xbuf[(GP) ^ 1][xw1]) = p1;             \
    }                                                                          \
    float oh0, oh1;                                                            \
    GATE1((S), gh0, cstate0, oh0);                                             \
    GATE1((2 + (S)), gh1, cstate1, oh1);                                       \
    const float wlS = ((S) == 0) ? wl0 : wl1;                                  \
    accout0 = __builtin_fmaf(oh0, wlS, accout0);                               \
    accout1 = __builtin_fmaf(oh1, wlS, accout1);                               \
    unsigned int hpk = cvt_pk_bf16(oh0, oh1);                                  \
    hbuf[0][(S) ^ 1][hw] = (unsigned short)hpk;                                \
    hbuf[1][(S) ^ 1][hw] = (unsigned short)(hpk >> 16);                        \
    if ((S) == 1) { wl0 = wlN0; wl1 = wlN1; }                                  \
    LBAR();                                                                    \
  } while (0)

__global__ __launch_bounds__(512, 2) void lstm_fused_kernel(
    const float* __restrict__ x,     // [2048,256,128]
    const float* __restrict__ w_ih,  // [512,128]
    const float* __restrict__ w_hh,  // [512,128]
    const float* __restrict__ b_ih,  // [512]
    const float* __restrict__ b_hh,  // [512]
    const float* __restrict__ w_lin, // [1, 256*128]
    const float* __restrict__ b_lin, // [1]
    float* __restrict__ out)         // [2048]
{
    // xbuf: bf16 [16 rows][128], row = batch*2 + step, swz ^((row&7)<<3)
    // hbuf: [stream][parity][4 rows][128], row = batch>>1, swz ^(row<<4)
    __shared__ __align__(16) unsigned short xbuf[2][16 * 128];
    __shared__ __align__(16) unsigned short hbuf[2][2][4 * 128];
    __shared__ float redout[8][8];

    const int tid  = threadIdx.x;
    const int wave = tid >> 6;      // 0..7
    const int lane = tid & 63;
    const int c16  = lane & 15;
    const int kq   = lane >> 4;     // 0..3
    const int row0 = blockIdx.x * 8;
    const int hid  = wave * 16 + c16;
    const int hcp  = c16 >> 2;      // compact h row (4-way broadcast)

    // zero hbuf (h0 = 0): 2*2*512*2B = 4KB = 512 threads x 8B
    reinterpret_cast<unsigned long long*>(hbuf)[tid] = 0ull;

    // ---- weights -> register B-fragments (bf16) ----
    // wave w, gate tile n, col c16: logical gate G = n*128 + w*16 + c16
    // K: kt<4 -> w_ih, kt>=4 -> w_hh
    short8 bq[8][4];
#pragma unroll
    for (int kt = 0; kt < 8; ++kt) {
#pragma unroll
        for (int n = 0; n < 4; ++n) {
            const int G  = n * 128 + wave * 16 + c16;
            const int k0 = kt * 32 + kq * 8;
            const float* src = (kt < 4) ? (w_ih + G * 128 + k0)
                                        : (w_hh + G * 128 + (k0 - 128));
            f32x4 lo = *reinterpret_cast<const f32x4*>(src);
            f32x4 hi = *reinterpret_cast<const f32x4*>(src + 4);
            bq[kt][n] = pack8(lo, hi);
        }
    }
    float bias[4];
#pragma unroll
    for (int n = 0; n < 4; ++n) {
        const int G = n * 128 + wave * 16 + c16;
        bias[n] = b_ih[G] + b_hh[G];
    }

    // x staging: wave w owns batch row w -> xbuf rows w*2 (s=0), w*2+1 (s=1)
    const int xr0 = wave * 2, xr1 = wave * 2 + 1;
    const int xw0 = (xr0 * 128 + lane * 2) ^ ((xr0 & 7) << 3);
    const int xw1 = (xr1 * 128 + lane * 2) ^ ((xr1 & 7) << 3);
    const float* xrow = x + (size_t)(row0 + wave) * T_STEPS * 128 + lane * 2;

    // prologue: stage x[0], x[1] into xbuf[0]
    {
        f32x2 v0 = *reinterpret_cast<const f32x2*>(xrow);
        f32x2 v1 = *reinterpret_cast<const f32x2*>(xrow + 128);
        *reinterpret_cast<unsigned int*>(&xbuf[0][xw0]) = cvt_pk_bf16(v0[0], v0[1]);
        *reinterpret_cast<unsigned int*>(&xbuf[0][xw1]) = cvt_pk_bf16(v1[0], v1[1]);
    }

    // lane (c16,kq): elem0 = batch 2kq (stream0), elem1 = batch 2kq+1 (stream1)
    float cstate0 = 0.f, cstate1 = 0.f;
    float accout0 = 0.f, accout1 = 0.f;
    float wl0 = w_lin[hid];
    float wl1 = w_lin[128 + hid];
    float wlN0 = 0.f, wlN1 = 0.f;
    f32x2 nx0 = {0.f, 0.f}, nx1 = {0.f, 0.f};
    f32x4 gX[4];
    const int hw = (kq * 128 + hid) ^ (kq << 4);  // compact h write (row kq)

    __syncthreads();  // zeros + x[0..1] staged

    for (int t = 0; t < T_STEPS; t += 4) {
        STEP(t,     0, 0);
        STEP(t,     1, 0);
        STEP(t + 2, 0, 1);
        STEP(t + 2, 1, 1);
    }

    // ---- reduce accout over hid: 16-lane tree, then across waves ----
#pragma unroll
    for (int r = 0; r < 2; ++r) {
        float v = (r == 0) ? accout0 : accout1;
        v += __shfl_xor(v, 1);
        v += __shfl_xor(v, 2);
        v += __shfl_xor(v, 4);
        v += __shfl_xor(v, 8);
        if (c16 == 0) redout[wave][2 * kq + r] = v;  // batch row 2kq+r
    }
    __syncthreads();
    if (tid < 8) {
        float s = b_lin[0];
#pragma unroll
        for (int w = 0; w < 8; ++w) s += redout[w][tid];
        out[row0 + tid] = s;
    }
}

extern "C" void kernel_launch(void* const* d_in, const int* in_sizes, int n_in,
                              void* d_out, int out_size, void* d_ws, size_t ws_size,
                              hipStream_t stream) {
    const float* x     = (const float*)d_in[0];
    const float* w_ih  = (const float*)d_in[1];
    const float* w_hh  = (const float*)d_in[2];
    const float* b_ih  = (const float*)d_in[3];
    const float* b_hh  = (const float*)d_in[4];
    const float* w_lin = (const float*)d_in[5];
    const float* b_lin = (const float*)d_in[6];
    float* out = (float*)d_out;

    lstm_fused_kernel<<<256, 512, 0, stream>>>(x, w_ih, w_hh, b_ih, b_hh, w_lin, b_lin, out);
}

// Round 9
// 199.602 us; speedup vs baseline: 1.3042x; 1.3042x over previous
//
#include <hip/hip_runtime.h>

// BiLSTM: LSTM(B=2048,T=256,F=H=128) + linear head, fused, one block/CU.
// Round 9 (round-8 compile fix): round-5 structure + (a) pipelined gX:
// x-gates for group g+1 accumulated during group g, used as the MFMA C-SEED
// of the h-chain (zero gate-combine adds, x-MFMA off the critical path,
// fills gate-math VALU phase via the separate matrix pipe); (b) x A-row =
// batch*2+step so gX rows align with h-chain D rows (r=2j+s); (c)
// s_setprio(1) around the h-MFMA cluster to stagger the 2 waves/SIMD.

typedef __attribute__((ext_vector_type(8))) short short8;
typedef __attribute__((ext_vector_type(4))) float f32x4;
typedef __attribute__((ext_vector_type(2))) float f32x2;

#define T_STEPS 256
#define L2E 1.4426950408889634f

__device__ __forceinline__ unsigned int cvt_pk_bf16(float lo, float hi) {
    unsigned int r;
    asm volatile("v_cvt_pk_bf16_f32 %0, %1, %2" : "=v"(r) : "v"(lo), "v"(hi));
    return r;
}
__device__ __forceinline__ unsigned short f2bf(float f) {
    unsigned int u = __builtin_bit_cast(unsigned int, f);
    u += 0x7fffu + ((u >> 16) & 1u);   // RNE
    return (unsigned short)(u >> 16);
}
__device__ __forceinline__ float rcp_fast(float x) { return __builtin_amdgcn_rcpf(x); }
__device__ __forceinline__ float exp2f_fast(float x) { return __builtin_amdgcn_exp2f(x); }

__device__ __forceinline__ short8 pack8(const f32x4 a, const f32x4 b) {
    short8 v;
    v[0] = (short)f2bf(a[0]); v[1] = (short)f2bf(a[1]);
    v[2] = (short)f2bf(a[2]); v[3] = (short)f2bf(a[3]);
    v[4] = (short)f2bf(b[0]); v[5] = (short)f2bf(b[1]);
    v[6] = (short)f2bf(b[2]); v[7] = (short)f2bf(b[3]);
    return v;
}

// barrier that drains LDS ops only; VMEM prefetches stay in flight
#define LBAR() asm volatile("s_waitcnt lgkmcnt(0)\n\ts_barrier" ::: "memory")

#define MFMA16(A, B, C) __builtin_amdgcn_mfma_f32_16x16x32_bf16((A), (B), (C), 0, 0, 0)

// gates for element j at D-row R; ch0/ch1 in scope. 5 exp + 2 rcp.
#define GATE(R, CS, WL, AJ, HO)                                                \
  { float gi = ch0[0][R] + ch1[0][R];                                          \
    float gf = ch0[1][R] + ch1[1][R];                                          \
    float gg = ch0[2][R] + ch1[2][R];                                          \
    float go = ch0[3][R] + ch1[3][R];                                          \
    float ef = exp2f_fast(gf * L2E);                                           \
    float ei = exp2f_fast(gi * L2E);                                           \
    float eg = exp2f_fast(gg * (2.f * L2E));                                   \
    float Fq = ef + 1.f, Iq = ei + 1.f, Gq = eg + 1.f;                         \
    float pq = Iq * Gq;                                                        \
    float Rq = rcp_fast(Fq * pq);                                              \
    float cq = __builtin_fmaf(ef * pq, (CS), (ei * Fq) * (eg - 1.f)) * Rq;     \
    (CS) = cq;                                                                 \
    float ccq = fminf(fmaxf(cq, -15.f), 15.f);                                 \
    float eo = exp2f_fast(go * L2E);                                           \
    float ec = exp2f_fast(ccq * (2.f * L2E));                                  \
    float oh = (eo * (ec - 1.f)) * rcp_fast((eo + 1.f) * (ec + 1.f));          \
    (AJ) = __builtin_fmaf(oh, (WL), (AJ));                                     \
    (HO) = oh; }

// One 2-step group. T0 even group start, GP = (T0>>1)&1.
// GXC: this group's x-gates (ready). GXN: accumulate next group's x-gates.
// hbuf: step0 reads [0] writes [1]; step1 reads [1] writes [0].
#define GROUP(T0, GP, GXC, GXN)                                                \
  do {                                                                         \
    const f32x4 zero4 = {0.f, 0.f, 0.f, 0.f};                                  \
    short8 afh[4], afx0, afx1;                                                 \
    f32x4 ch0[4], ch1[4];                                                      \
    /* ================= step 0 (s=0) ================= */                     \
    _Pragma("unroll")                                                          \
    for (int kt = 0; kt < 4; ++kt)                                             \
      afh[kt] = *reinterpret_cast<const short8*>(&hbuf[0][hridx[kt]]);         \
    __builtin_amdgcn_s_setprio(1);                                             \
    _Pragma("unroll")                                                          \
    for (int n = 0; n < 4; ++n) ch0[n] = MFMA16(afh[0], bq[4][n], GXC[n]);     \
    _Pragma("unroll")                                                          \
    for (int n = 0; n < 4; ++n) ch1[n] = MFMA16(afh[2], bq[6][n], zero4);      \
    _Pragma("unroll")                                                          \
    for (int n = 0; n < 4; ++n) ch0[n] = MFMA16(afh[1], bq[5][n], ch0[n]);     \
    _Pragma("unroll")                                                          \
    for (int n = 0; n < 4; ++n) ch1[n] = MFMA16(afh[3], bq[7][n], ch1[n]);     \
    __builtin_amdgcn_s_setprio(0);                                             \
    /* x-gates for NEXT group, first half (filler for gate-math phase) */      \
    afx0 = *reinterpret_cast<const short8*>(&xbuf[GP][xridx[0]]);              \
    afx1 = *reinterpret_cast<const short8*>(&xbuf[GP][xridx[1]]);              \
    _Pragma("unroll")                                                          \
    for (int n = 0; n < 4; ++n)                                                \
      GXN[n] = (f32x4){bias[n], bias[n], bias[n], bias[n]};                    \
    _Pragma("unroll")                                                          \
    for (int n = 0; n < 4; ++n) GXN[n] = MFMA16(afx0, bq[0][n], GXN[n]);       \
    _Pragma("unroll")                                                          \
    for (int n = 0; n < 4; ++n) GXN[n] = MFMA16(afx1, bq[1][n], GXN[n]);       \
    { /* prefetch x for group T0+4 and w_lin for T0+2/3 */                     \
      const int tt = ((T0) + 4 < T_STEPS) ? (T0) + 4 : 0;                      \
      nx0 = *reinterpret_cast<const f32x2*>(xrow + (size_t)tt * 128);          \
      nx1 = *reinterpret_cast<const f32x2*>(xrow + (size_t)(tt + 1) * 128);    \
      const int tw = ((T0) + 2 < T_STEPS) ? (T0) + 2 : 0;                      \
      wlN0 = w_lin[tw * 128 + hid];                                            \
      wlN1 = w_lin[(tw + 1) * 128 + hid];                                      \
    }                                                                          \
    { float h0, h1;                                                            \
      GATE(0, cst0, wlA, acc0, h0);                                            \
      GATE(2, cst1, wlA, acc1, h1);                                            \
      unsigned int hpk = cvt_pk_bf16(h0, h1);                                  \
      hbuf[1][hwidx0] = (unsigned short)hpk;                                   \
      hbuf[1][hwidx1] = (unsigned short)(hpk >> 16); }                         \
    LBAR();                                                                    \
    /* ================= step 1 (s=1) ================= */                     \
    _Pragma("unroll")                                                          \
    for (int kt = 0; kt < 4; ++kt)                                             \
      afh[kt] = *reinterpret_cast<const short8*>(&hbuf[1][hridx[kt]]);         \
    __builtin_amdgcn_s_setprio(1);                                             \
    _Pragma("unroll")                                                          \
    for (int n = 0; n < 4; ++n) ch0[n] = MFMA16(afh[0], bq[4][n], GXC[n]);     \
    _Pragma("unroll")                                                          \
    for (int n = 0; n < 4; ++n) ch1[n] = MFMA16(afh[2], bq[6][n], zero4);      \
    _Pragma("unroll")                                                          \
    for (int n = 0; n < 4; ++n) ch0[n] = MFMA16(afh[1], bq[5][n], ch0[n]);     \
    _Pragma("unroll")                                                          \
    for (int n = 0; n < 4; ++n) ch1[n] = MFMA16(afh[3], bq[7][n], ch1[n]);     \
    __builtin_amdgcn_s_setprio(0);                                             \
    /* x-gates for NEXT group, second half */                                  \
    afx0 = *reinterpret_cast<const short8*>(&xbuf[GP][xridx[2]]);              \
    afx1 = *reinterpret_cast<const short8*>(&xbuf[GP][xridx[3]]);              \
    _Pragma("unroll")                                                          \
    for (int n = 0; n < 4; ++n) GXN[n] = MFMA16(afx0, bq[2][n], GXN[n]);       \
    _Pragma("unroll")                                                          \
    for (int n = 0; n < 4; ++n) GXN[n] = MFMA16(afx1, bq[3][n], GXN[n]);       \
    { /* stage x(T0+4) into the other xbuf */                                  \
      *reinterpret_cast<unsigned int*>(&xbuf[(GP) ^ 1][xw0]) =                 \
          cvt_pk_bf16(nx0[0], nx0[1]);                                         \
      *reinterpret_cast<unsigned int*>(&xbuf[(GP) ^ 1][xw1]) =                 \
          cvt_pk_bf16(nx1[0], nx1[1]); }                                       \
    { float h0, h1;                                                            \
      GATE(1, cst0, wlB, acc0, h0);                                            \
      GATE(3, cst1, wlB, acc1, h1);                                            \
      unsigned int hpk = cvt_pk_bf16(h0, h1);                                  \
      hbuf[0][hwidx0] = (unsigned short)hpk;                                   \
      hbuf[0][hwidx1] = (unsigned short)(hpk >> 16); }                         \
    wlA = wlN0; wlB = wlN1;                                                    \
    LBAR();                                                                    \
  } while (0)

__global__ __launch_bounds__(512, 2) void lstm_fused_kernel(
    const float* __restrict__ x,     // [2048,256,128]
    const float* __restrict__ w_ih,  // [512,128]
    const float* __restrict__ w_hh,  // [512,128]
    const float* __restrict__ b_ih,  // [512]
    const float* __restrict__ b_hh,  // [512]
    const float* __restrict__ w_lin, // [1, 256*128]
    const float* __restrict__ b_lin, // [1]
    float* __restrict__ out)         // [2048]
{
    // xbuf: bf16 [16 rows][128], row = batch*2 + step-in-group, swz ^((r&7)<<3)
    // hbuf: bf16 [parity][8 rows][128], row = batch, swz ^(row<<3)
    __shared__ __align__(16) unsigned short xbuf[2][16 * 128];
    __shared__ __align__(16) unsigned short hbuf[2][8 * 128];
    __shared__ float redout[8][8];

    const int tid  = threadIdx.x;
    const int wave = tid >> 6;      // 0..7
    const int lane = tid & 63;
    const int c16  = lane & 15;
    const int kq   = lane >> 4;     // 0..3
    const int row0 = blockIdx.x * 8;
    const int hid  = wave * 16 + c16;

    // zero hbuf (h0=0): 2*8*128*2B = 4KB
    reinterpret_cast<unsigned long long*>(hbuf)[tid] = 0ull;

    // ---- weights -> register B-fragments (bf16) ----
    // wave w, gate tile n, col c16: logical gate G = n*128 + w*16 + c16
    // K: kt<4 -> w_ih, kt>=4 -> w_hh
    short8 bq[8][4];
#pragma unroll
    for (int kt = 0; kt < 8; ++kt) {
#pragma unroll
        for (int n = 0; n < 4; ++n) {
            const int G  = n * 128 + wave * 16 + c16;
            const int k0 = kt * 32 + kq * 8;
            const float* src = (kt < 4) ? (w_ih + G * 128 + k0)
                                        : (w_hh + G * 128 + (k0 - 128));
            f32x4 lo = *reinterpret_cast<const f32x4*>(src);
            f32x4 hi = *reinterpret_cast<const f32x4*>(src + 4);
            bq[kt][n] = pack8(lo, hi);
        }
    }
    float bias[4];
#pragma unroll
    for (int n = 0; n < 4; ++n) {
        const int G = n * 128 + wave * 16 + c16;
        bias[n] = b_ih[G] + b_hh[G];
    }

    // A-frag read indices (loop-invariant):
    //   x: A-row c16 (row = batch*2+step) -> lane (c16,kq) D rows 4kq+r,
    //      element (batch 2kq+j, step s) at r = 2j+s
    //   h: A-row c16 must hold h[batch c16>>1] -> read compact row c16>>1
    //      (pairs (2b,2b+1) broadcast, free)
    int xridx[4], hridx[4];
    const int hcr = c16 >> 1;
#pragma unroll
    for (int kt = 0; kt < 4; ++kt) {
        xridx[kt] = (c16 * 128 + kt * 32 + kq * 8) ^ ((c16 & 7) << 3);
        hridx[kt] = hcr * 128 + ((kt * 32 + kq * 8) ^ (hcr << 3));
    }

    // x staging: wave w owns batch w -> xbuf rows 2w (s=0), 2w+1 (s=1)
    const int xr0 = wave * 2, xr1 = wave * 2 + 1;
    const int xw0 = (xr0 * 128 + lane * 2) ^ ((xr0 & 7) << 3);
    const int xw1 = (xr1 * 128 + lane * 2) ^ ((xr1 & 7) << 3);
    const float* xrow = x + (size_t)(row0 + wave) * T_STEPS * 128 + lane * 2;

    // h write: lane (c16,kq) owns batches 2kq+j at col hid
    const int hwidx0 = ((2 * kq + 0) * 128 + hid) ^ ((2 * kq + 0) << 3);
    const int hwidx1 = ((2 * kq + 1) * 128 + hid) ^ ((2 * kq + 1) << 3);

    // ---- prologue ----
    // stage x(t0,t1) -> xbuf[1] (temp); x(t2,t3) -> xbuf[0] (g0 reads GP=0)
    {
        f32x2 v0 = *reinterpret_cast<const f32x2*>(xrow);
        f32x2 v1 = *reinterpret_cast<const f32x2*>(xrow + 128);
        *reinterpret_cast<unsigned int*>(&xbuf[1][xw0]) = cvt_pk_bf16(v0[0], v0[1]);
        *reinterpret_cast<unsigned int*>(&xbuf[1][xw1]) = cvt_pk_bf16(v1[0], v1[1]);
    }
    __syncthreads();

    f32x4 gA[4], gB[4];
    {   // gA = bias + x(t0,t1)·w_ih  (from xbuf[1])
        short8 afx[4];
#pragma unroll
        for (int kt = 0; kt < 4; ++kt)
            afx[kt] = *reinterpret_cast<const short8*>(&xbuf[1][xridx[kt]]);
#pragma unroll
        for (int n = 0; n < 4; ++n)
            gA[n] = (f32x4){bias[n], bias[n], bias[n], bias[n]};
#pragma unroll
        for (int kt = 0; kt < 4; ++kt)
#pragma unroll
            for (int n = 0; n < 4; ++n)
                gA[n] = MFMA16(afx[kt], bq[kt][n], gA[n]);
    }
    {
        f32x2 v2 = *reinterpret_cast<const f32x2*>(xrow + 2 * 128);
        f32x2 v3 = *reinterpret_cast<const f32x2*>(xrow + 3 * 128);
        *reinterpret_cast<unsigned int*>(&xbuf[0][xw0]) = cvt_pk_bf16(v2[0], v2[1]);
        *reinterpret_cast<unsigned int*>(&xbuf[0][xw1]) = cvt_pk_bf16(v3[0], v3[1]);
    }

    float cst0 = 0.f, cst1 = 0.f;
    float acc0 = 0.f, acc1 = 0.f;
    float wlA = w_lin[hid];
    float wlB = w_lin[128 + hid];
    float wlN0 = 0.f, wlN1 = 0.f;
    f32x2 nx0 = {0.f, 0.f}, nx1 = {0.f, 0.f};

    __syncthreads();  // hbuf zeros + xbuf[0] staged

    for (int t = 0; t < T_STEPS; t += 4) {
        GROUP(t,     0, gA, gB);
        GROUP(t + 2, 1, gB, gA);
    }

    // ---- reduce accout over hid: 16-lane tree, then across waves ----
#pragma unroll
    for (int r = 0; r < 2; ++r) {
        float v = (r == 0) ? acc0 : acc1;
        v += __shfl_xor(v, 1);
        v += __shfl_xor(v, 2);
        v += __shfl_xor(v, 4);
        v += __shfl_xor(v, 8);
        if (c16 == 0) redout[wave][2 * kq + r] = v;  // batch row 2kq+r
    }
    __syncthreads();
    if (tid < 8) {
        float s = b_lin[0];
#pragma unroll
        for (int w = 0; w < 8; ++w) s += redout[w][tid];
        out[row0 + tid] = s;
    }
}

extern "C" void kernel_launch(void* const* d_in, const int* in_sizes, int n_in,
                              void* d_out, int out_size, void* d_ws, size_t ws_size,
                              hipStream_t stream) {
    const float* x     = (const float*)d_in[0];
    const float* w_ih  = (const float*)d_in[1];
    const float* w_hh  = (const float*)d_in[2];
    const float* b_ih  = (const float*)d_in[3];
    const float* b_hh  = (const float*)d_in[4];
    const float* w_lin = (const float*)d_in[5];
    const float* b_lin = (const float*)d_in[6];
    float* out = (float*)d_out;

    lstm_fused_kernel<<<256, 512, 0, stream>>>(x, w_ih, w_hh, b_ih, b_hh, w_lin, b_lin, out);
}